// Round 12
// baseline (255.807 us; speedup 1.0000x reference)
//
#include <hip/hip_runtime.h>
#include <stdint.h>

#define B_ 2
#define S_ 2048
#define D_ 1024
#define H_ 16
#define HD_ 64
#define MG_ (B_*S_)
#define MASKV -1000000.0f
#define LP_ 72   // Ps row stride (bf16): conflict-free b128
#define LO_ 68   // merge buffer row stride (f32)
#define M2_ 17.3f  // fixed softmax max, log2 domain
#define QSCALE_ (0.125f * 1.44269504088896f)  // 1/sqrt(HD) * log2(e)

typedef __bf16 bf16;
typedef bf16 bf16x8 __attribute__((ext_vector_type(8)));
typedef bf16 bf16x4 __attribute__((ext_vector_type(4)));
typedef float f32x4 __attribute__((ext_vector_type(4)));

#define MFMA(a, b, c) __builtin_amdgcn_mfma_f32_16x16x32_bf16(a, b, c, 0, 0, 0)

// async global->LDS, 16 B per lane; lds dest = wave-uniform base + lane*16
__device__ __forceinline__ void gl_lds16(const bf16* g, bf16* l) {
  __builtin_amdgcn_global_load_lds((const __attribute__((address_space(1))) void*)g,
                                   (__attribute__((address_space(3))) void*)l, 16, 0, 0);
}

// K rows needed per batch: keys >= ceil64(valid) are unobservable (P==0 exactly).
// valid==0 -> reference does uniform softmax over ALL positions -> need everything.
__device__ __forceinline__ int kneed_of(int valid) {
  return (valid == 0) ? S_ : ((valid + 63) & ~63);
}

// ---------------- fused front end ----------------
// planes 0..3: WT[n][k] = (bf16)W[k][n]  (32x32 transpose tiles)
// planes 4..6: Q/K/V f32->bf16 cast (Q pre-scaled); K/V strips beyond
//              ceil128(kneed) skipped (proj reads full 128-row strips).
__global__ __launch_bounds__(256) void front_kernel(const float* __restrict__ W0, const float* __restrict__ W1,
                                                    const float* __restrict__ W2, const float* __restrict__ W3,
                                                    bf16* __restrict__ T, const float* __restrict__ Qin,
                                                    const float* __restrict__ Kin, const float* __restrict__ Vin,
                                                    bf16* __restrict__ qb, bf16* __restrict__ kb,
                                                    bf16* __restrict__ vb, const int* __restrict__ vlen) {
  __shared__ float tile[32][33];
  int z = blockIdx.y;
  if (z < 4) {
    const float* W = z == 0 ? W0 : z == 1 ? W1 : z == 2 ? W2 : W3;
    bf16* Tz = T + (size_t)z * D_ * D_;
    int tx = threadIdx.x & 31, ty = threadIdx.x >> 5;
    int bn = (blockIdx.x & 31) * 32, bk = (blockIdx.x >> 5) * 32;
#pragma unroll
    for (int i = 0; i < 32; i += 8)
      tile[ty + i][tx] = W[(size_t)(bk + ty + i) * D_ + bn + tx];
    __syncthreads();
#pragma unroll
    for (int i = 0; i < 32; i += 8)
      Tz[(size_t)(bn + ty + i) * D_ + bk + tx] = (bf16)tile[tx][ty + i];
  } else {
    int t = z - 4;
    const float* src = t == 0 ? Qin : t == 1 ? Kin : Vin;
    bf16* dst = t == 0 ? qb : t == 1 ? kb : vb;
    float sc = t == 0 ? QSCALE_ : 1.0f;
    if (t) {  // K/V: skip strips no proj block will read
      int m0 = blockIdx.x * 4;  // 4 tokens per block
      int b = m0 >> 11, s0 = m0 & (S_ - 1);
      int kneed128 = (kneed_of(vlen[b]) + 127) & ~127;
      if (s0 >= kneed128) return;
    }
    size_t base4 = (size_t)blockIdx.x * 1024 + threadIdx.x;  // float4 index
#pragma unroll
    for (int j = 0; j < 4; ++j) {
      size_t i4 = base4 + (size_t)j * 256;
      float4 v = *(const float4*)&src[i4 * 4];
      bf16x4 bv; bv[0] = (bf16)(v.x * sc); bv[1] = (bf16)(v.y * sc);
      bv[2] = (bf16)(v.z * sc); bv[3] = (bf16)(v.w * sc);
      *(bf16x4*)&dst[i4 * 4] = bv;
    }
  }
}

// ---------------- fused projections, pure-bf16, both operands async, vlen-gated ----------------
// mode 0: qh = qb @ Wq (qb pre-scaled) ; mode 1: kh = kb @ Wk ; mode 2: vT = (vb @ Wv)^T
// modes 1/2: token strips with s0 >= kneed produce only unobservable K/V rows -> skip.
__global__ __launch_bounds__(256) void proj_gemm_b(const bf16* __restrict__ qb, const bf16* __restrict__ kb,
                                                   const bf16* __restrict__ vb, const bf16* __restrict__ WT,
                                                   bf16* __restrict__ qh, bf16* __restrict__ kh,
                                                   bf16* __restrict__ vT, const int* __restrict__ vlen) {
  __shared__ alignas(16) bf16 Sa[128 * 32];  // token rows
  __shared__ alignas(16) bf16 Sw[128 * 32];  // WT rows
  int mode = blockIdx.y;
  int bx = blockIdx.x;
  int i1 = (bx & 7) + ((bx >> 6) << 3);  // heavy strip (tokens), 0..31
  int i2 = (bx >> 3) & 7;                // light strip (WT), 0..7
  if (mode >= 1) {
    int m0tok = i1 * 128;
    int b = m0tok >> 11, s0 = m0tok & (S_ - 1);
    if (s0 >= kneed_of(vlen[b])) return;
  }
  int tid = threadIdx.x, lane = tid & 63, w = tid >> 6;
  int wm = w >> 1, wn = w & 1, ml = lane & 15, quad = lane >> 4;
  int l4 = lane >> 2, k8 = (lane & 3) * 8;
  f32x4 acc[4][4] = {};

  const bf16* Tok = mode == 0 ? qb : mode == 1 ? kb : vb;
  const bf16* Hp = WT + (size_t)mode * D_ * D_;
  int frow0 = i1 * 128, hrow0 = i2 * 128;
  bf16* Xs = (mode < 2) ? Sa : Sw;  // MFMA A-side
  bf16* Ys = (mode < 2) ? Sw : Sa;  // MFMA B-side

  for (int kk = 0; kk < D_; kk += 32) {
    __syncthreads();
#pragma unroll
    for (int j = 0; j < 2; ++j) {
      int chunk = w * 2 + j;
      gl_lds16(&Tok[(size_t)(frow0 + chunk * 16 + l4) * D_ + kk + k8], &Sa[chunk * 16 * 32]);
      gl_lds16(&Hp[(size_t)(hrow0 + chunk * 16 + l4) * D_ + kk + k8], &Sw[chunk * 16 * 32]);
    }
    __syncthreads();
    bf16x8 af[4], bfr[4];
#pragma unroll
    for (int mt = 0; mt < 4; ++mt) af[mt] = *(bf16x8*)&Xs[(wm * 64 + mt * 16 + ml) * 32 + quad * 8];
#pragma unroll
    for (int nt = 0; nt < 4; ++nt) bfr[nt] = *(bf16x8*)&Ys[(wn * 64 + nt * 16 + ml) * 32 + quad * 8];
#pragma unroll
    for (int mt = 0; mt < 4; ++mt)
#pragma unroll
      for (int nt = 0; nt < 4; ++nt)
        acc[mt][nt] = MFMA(af[mt], bfr[nt], acc[mt][nt]);
  }

  if (mode < 2) {
    bf16* dst = mode ? kh : qh;
    int m0 = i1 * 128, n0 = i2 * 128;
#pragma unroll
    for (int mt = 0; mt < 4; ++mt)
#pragma unroll
      for (int nt = 0; nt < 4; ++nt)
#pragma unroll
        for (int r = 0; r < 4; ++r) {
          int m = m0 + wm * 64 + mt * 16 + quad * 4 + r;
          int n = n0 + wn * 64 + nt * 16 + ml;
          int b = m >> 11, s = m & (S_ - 1), h = n >> 6, hd = n & 63;
          dst[(((size_t)(b * H_ + h)) * S_ + s) * HD_ + hd] = (bf16)acc[mt][nt][r];
        }
  } else {
    int m0 = i2 * 128, n0 = i1 * 128;
#pragma unroll
    for (int mt = 0; mt < 4; ++mt)
#pragma unroll
      for (int nt = 0; nt < 4; ++nt)
#pragma unroll
        for (int r = 0; r < 4; ++r) {
          int dcol = m0 + wm * 64 + mt * 16 + quad * 4 + r;  // d
          int n = n0 + wn * 64 + nt * 16 + ml;               // token
          int b = n >> 11, s = n & (S_ - 1), h = dcol >> 6, hd = dcol & 63;
          vT[(((size_t)(b * H_ + h)) * HD_ + hd) * S_ + s] = (bf16)acc[mt][nt][r];
        }
  }
}

// ---------------- fallback wcast (small-ws path only) ----------------
__global__ __launch_bounds__(256) void wcast_kernel(const float* __restrict__ W0, const float* __restrict__ W1,
                                                    const float* __restrict__ W2, const float* __restrict__ W3,
                                                    bf16* __restrict__ T) {
  const float* W = blockIdx.z == 0 ? W0 : blockIdx.z == 1 ? W1 : blockIdx.z == 2 ? W2 : W3;
  bf16* Tz = T + (size_t)blockIdx.z * D_ * D_;
  __shared__ float tile[32][33];
  int tx = threadIdx.x & 31, ty = threadIdx.x >> 5;
  int bn = blockIdx.x * 32, bk = blockIdx.y * 32;
#pragma unroll
  for (int i = 0; i < 32; i += 8)
    tile[ty + i][tx] = W[(size_t)(bk + ty + i) * D_ + bn + tx];
  __syncthreads();
#pragma unroll
  for (int i = 0; i < 32; i += 8)
    Tz[(size_t)(bn + ty + i) * D_ + bk + tx] = (bf16)tile[tx][ty + i];
}

// ---------------- fallback projections (round-5 exact, f32 inputs) ----------------
__global__ __launch_bounds__(256) void proj_gemm(const float* __restrict__ Qin, const float* __restrict__ Kin,
                                                 const float* __restrict__ Vin, const bf16* __restrict__ WT,
                                                 bf16* __restrict__ qh, bf16* __restrict__ kh,
                                                 bf16* __restrict__ vT) {
  __shared__ alignas(16) bf16 Asf[128 * 32];
  __shared__ alignas(16) bf16 Ash[128 * 32];
  int mode = blockIdx.y;
  int bx = blockIdx.x;
  int i1 = (bx & 7) + ((bx >> 6) << 3);
  int i2 = (bx >> 3) & 7;
  int tid = threadIdx.x, lane = tid & 63, w = tid >> 6;
  int wm = w >> 1, wn = w & 1, ml = lane & 15, quad = lane >> 4;
  int rr = tid >> 3, c4 = (tid & 7) * 4;
  int l4 = lane >> 2, k8 = (lane & 3) * 8;
  f32x4 acc[4][4] = {};

  const float* Fp = mode == 0 ? Qin : mode == 1 ? Kin : Vin;
  const bf16* Hp = WT + (size_t)mode * D_ * D_;
  int frow0 = i1 * 128, hrow0 = i2 * 128;
  bf16* Xs = (mode < 2) ? Asf : Ash;
  bf16* Ys = (mode < 2) ? Ash : Asf;

  for (int kk = 0; kk < D_; kk += 32) {
    __syncthreads();
#pragma unroll
    for (int j = 0; j < 2; ++j) {
      int chunk = w * 2 + j;
      gl_lds16(&Hp[(size_t)(hrow0 + chunk * 16 + l4) * D_ + kk + k8], &Ash[chunk * 16 * 32]);
    }
#pragma unroll
    for (int p = 0; p < 4; ++p) {
      float4 v = *(const float4*)&Fp[(size_t)(frow0 + rr + p * 32) * D_ + kk + c4];
      bf16x4 bv; bv[0] = (bf16)v.x; bv[1] = (bf16)v.y; bv[2] = (bf16)v.z; bv[3] = (bf16)v.w;
      *(bf16x4*)&Asf[(rr + p * 32) * 32 + c4] = bv;
    }
    __syncthreads();
    bf16x8 af[4], bfr[4];
#pragma unroll
    for (int mt = 0; mt < 4; ++mt) af[mt] = *(bf16x8*)&Xs[(wm * 64 + mt * 16 + ml) * 32 + quad * 8];
#pragma unroll
    for (int nt = 0; nt < 4; ++nt) bfr[nt] = *(bf16x8*)&Ys[(wn * 64 + nt * 16 + ml) * 32 + quad * 8];
#pragma unroll
    for (int mt = 0; mt < 4; ++mt)
#pragma unroll
      for (int nt = 0; nt < 4; ++nt)
        acc[mt][nt] = MFMA(af[mt], bfr[nt], acc[mt][nt]);
  }

  if (mode < 2) {
    bf16* dst = mode ? kh : qh;
    float oscale = mode ? 1.0f : QSCALE_;
    int m0 = i1 * 128, n0 = i2 * 128;
#pragma unroll
    for (int mt = 0; mt < 4; ++mt)
#pragma unroll
      for (int nt = 0; nt < 4; ++nt)
#pragma unroll
        for (int r = 0; r < 4; ++r) {
          int m = m0 + wm * 64 + mt * 16 + quad * 4 + r;
          int n = n0 + wn * 64 + nt * 16 + ml;
          int b = m >> 11, s = m & (S_ - 1), h = n >> 6, hd = n & 63;
          dst[(((size_t)(b * H_ + h)) * S_ + s) * HD_ + hd] = (bf16)(acc[mt][nt][r] * oscale);
        }
  } else {
    int m0 = i2 * 128, n0 = i1 * 128;
#pragma unroll
    for (int mt = 0; mt < 4; ++mt)
#pragma unroll
      for (int nt = 0; nt < 4; ++nt)
#pragma unroll
        for (int r = 0; r < 4; ++r) {
          int dcol = m0 + wm * 64 + mt * 16 + quad * 4 + r;
          int n = n0 + wn * 64 + nt * 16 + ml;
          int b = n >> 11, s = n & (S_ - 1), h = dcol >> 6, hd = dcol & 63;
          vT[(((size_t)(b * H_ + h)) * HD_ + hd) * S_ + s] = (bf16)acc[mt][nt][r];
        }
  }
}

// ---------------- barrier-free flash attention, fixed-max softmax ----------------
// Round-5 body exact; ONLY the bx decode changed: b from bx bit 3 so batches
// interleave at fine grain (per-CU load balance); bx&7 still pins each (b,h)
// to one XCD for K/V L2 residency.
__global__ __launch_bounds__(256) void attn_kernel(const bf16* __restrict__ qh, const bf16* __restrict__ kh,
                                                   const bf16* __restrict__ vT, const int* __restrict__ vlen,
                                                   bf16* __restrict__ ctx) {
  __shared__ alignas(16) char ldsraw[35328];
  bf16* Ps = (bf16*)ldsraw;                    // [4 waves][32 rows][LP_]
  float* Om = (float*)ldsraw;                  // [4 waves][32 rows][LO_] (union, post-loop)
  float* Lv = (float*)(ldsraw + 34816);        // [4 waves][32 rows]

  int tid = threadIdx.x, lane = tid & 63, w = tid >> 6;
  int ml = lane & 15, quad = lane >> 4;
  int wq = w >> 1, wk = w & 1;
  int bx = blockIdx.x;
  int h = (bx & 7) | (((bx >> 9) & 1) << 3);
  int b = (bx >> 3) & 1;                 // alternates every 8 blocks -> balanced CUs
  int qt = (bx >> 4) & 31;
  int bh = (b << 4) | h;
  const bf16* qbase = qh + ((size_t)bh * S_ + qt * 64 + wq * 32) * HD_;
  const bf16* kbase = kh + (size_t)bh * S_ * HD_;
  const bf16* vbase = vT + (size_t)bh * HD_ * S_;
  int valid = vlen[b];
  int nkt = (valid == 0) ? (S_ / 64) : ((valid + 63) >> 6);

  bf16x8 aq[2][2];
#pragma unroll
  for (int mt = 0; mt < 2; ++mt)
#pragma unroll
    for (int half = 0; half < 2; ++half)
      aq[mt][half] = *(const bf16x8*)&qbase[(mt * 16 + ml) * HD_ + half * 32 + quad * 8];

  bf16 onev = (bf16)1.0f;
  bf16x8 ones = {onev, onev, onev, onev, onev, onev, onev, onev};

  f32x4 o[2][4] = {};
  f32x4 lacc[2] = {};

  bf16* Pw = Ps + (size_t)w * 32 * LP_;

  for (int kt = wk; kt < nkt; kt += 2) {
    const bf16* kp = kbase + (size_t)kt * 64 * HD_;
    bool tail = (kt * 64 + 64 > valid);
    bf16x8 bk[4][2];
#pragma unroll
    for (int nt = 0; nt < 4; ++nt)
#pragma unroll
      for (int half = 0; half < 2; ++half)
        bk[nt][half] = *(const bf16x8*)&kp[(nt * 16 + ml) * HD_ + half * 32 + quad * 8];

#pragma unroll
    for (int mt = 0; mt < 2; ++mt) {
      f32x4 sc[4];
#pragma unroll
      for (int nt = 0; nt < 4; ++nt) {
        f32x4 c = {};
        c = MFMA(aq[mt][0], bk[nt][0], c);
        c = MFMA(aq[mt][1], bk[nt][1], c);
        sc[nt] = c;
      }
#pragma unroll
      for (int r = 0; r < 4; ++r) {
#pragma unroll
        for (int nt = 0; nt < 4; ++nt) {
          float s = sc[nt][r];
          if (tail) {
            int col = kt * 64 + nt * 16 + ml;
            if (col >= valid) s = MASKV;
          }
          if (valid == 0) s = 0.f;  // uniform softmax (all-masked case)
          float p = exp2f(s - M2_);
          Pw[(mt * 16 + quad * 4 + r) * LP_ + nt * 16 + ml] = (bf16)p;
        }
      }
    }
    // PV + l-sum: wave-private P (compiler inserts lgkmcnt wait; no barrier)
#pragma unroll
    for (int ks = 0; ks < 2; ++ks) {
      bf16x8 bv[4];
#pragma unroll
      for (int ht = 0; ht < 4; ++ht)
        bv[ht] = *(const bf16x8*)&vbase[(size_t)(ht * 16 + ml) * S_ + kt * 64 + ks * 32 + quad * 8];
#pragma unroll
      for (int mt = 0; mt < 2; ++mt) {
        bf16x8 ap = *(bf16x8*)&Pw[(mt * 16 + ml) * LP_ + ks * 32 + quad * 8];
        lacc[mt] = MFMA(ap, ones, lacc[mt]);
#pragma unroll
        for (int ht = 0; ht < 4; ++ht) o[mt][ht] = MFMA(ap, bv[ht], o[mt][ht]);
      }
    }
  }

  // ---- sum-merge across wk ----
  __syncthreads();  // all waves done with Ps (union with Om)
#pragma unroll
  for (int mt = 0; mt < 2; ++mt) {
#pragma unroll
    for (int r = 0; r < 4; ++r) {
      int rl = mt * 16 + quad * 4 + r;
#pragma unroll
      for (int ht = 0; ht < 4; ++ht)
        Om[(w * 32 + rl) * LO_ + ht * 16 + ml] = o[mt][ht][r];
      if (ml == 0) Lv[w * 32 + rl] = lacc[mt][r];
    }
  }
  __syncthreads();
#pragma unroll 4
  for (int rr = 0; rr < 16; ++rr) {
    int rg = w * 16 + rr;
    int wqs = rg >> 5, rl = rg & 31;
    int s0 = (wqs * 2) * 32 + rl, s1 = (wqs * 2 + 1) * 32 + rl;
    float ls = Lv[s0] + Lv[s1];
    float ov = Om[s0 * LO_ + lane] + Om[s1 * LO_ + lane];
    ctx[((size_t)b * S_ + qt * 64 + rg) * D_ + h * 64 + lane] = (bf16)(ov / ls);
  }
}

// ---------------- output projection: 128x64 tiles, async staging, XCD-swizzled ----------------
__global__ __launch_bounds__(256) void out_gemm(const bf16* __restrict__ ctx, const bf16* __restrict__ WoT,
                                                float* __restrict__ out) {
  __shared__ alignas(16) bf16 As[128 * 32];
  __shared__ alignas(16) bf16 Bs[64 * 32];
  int bx = blockIdx.x;  // flat 512
  int mt8 = (bx & 7) + ((bx >> 7) << 3);  // m-tile 0..31 (same-m -> same XCD)
  int ntile = (bx >> 3) & 15;             // n-tile 0..15
  int tid = threadIdx.x, lane = tid & 63, w = tid >> 6;
  int wm = w >> 1, wn = w & 1, ml = lane & 15, quad = lane >> 4;
  int l4 = lane >> 2, k8 = (lane & 3) * 8;
  int m0 = mt8 * 128, n0 = ntile * 64;
  f32x4 acc[4][2] = {};
  for (int kk = 0; kk < D_; kk += 32) {
    __syncthreads();
#pragma unroll
    for (int j = 0; j < 2; ++j) {
      int chunk = w * 2 + j;
      gl_lds16(&ctx[(size_t)(m0 + chunk * 16 + l4) * D_ + kk + k8], &As[chunk * 16 * 32]);
    }
    gl_lds16(&WoT[(size_t)(n0 + w * 16 + l4) * D_ + kk + k8], &Bs[w * 16 * 32]);
    __syncthreads();
    bf16x8 af[4], bfr[2];
#pragma unroll
    for (int mt = 0; mt < 4; ++mt) af[mt] = *(bf16x8*)&As[(wm * 64 + mt * 16 + ml) * 32 + quad * 8];
#pragma unroll
    for (int nt = 0; nt < 2; ++nt) bfr[nt] = *(bf16x8*)&Bs[(wn * 32 + nt * 16 + ml) * 32 + quad * 8];
#pragma unroll
    for (int mt = 0; mt < 4; ++mt)
#pragma unroll
      for (int nt = 0; nt < 2; ++nt)
        acc[mt][nt] = MFMA(af[mt], bfr[nt], acc[mt][nt]);
  }
#pragma unroll
  for (int mt = 0; mt < 4; ++mt)
#pragma unroll
    for (int nt = 0; nt < 2; ++nt)
#pragma unroll
      for (int r = 0; r < 4; ++r) {
        int m = m0 + wm * 64 + mt * 16 + quad * 4 + r;
        int n = n0 + wn * 32 + nt * 16 + ml;
        out[(size_t)m * D_ + n] = acc[mt][nt][r];
      }
}

extern "C" void kernel_launch(void* const* d_in, const int* in_sizes, int n_in,
                              void* d_out, int out_size, void* d_ws, size_t ws_size,
                              hipStream_t stream) {
  const float* Q = (const float*)d_in[0];
  const float* K = (const float*)d_in[1];
  const float* V = (const float*)d_in[2];
  const int* vl = (const int*)d_in[3];
  const float* Wq = (const float*)d_in[4];
  const float* Wk = (const float*)d_in[5];
  const float* Wv = (const float*)d_in[6];
  const float* Wo = (const float*)d_in[7];
  char* ws = (char*)d_ws;
  bf16* WT  = (bf16*)ws;                                // 4 x 2MB (WqT, WkT, WvT, WoT)
  bf16* qh  = (bf16*)(ws + 8ull * 1024 * 1024);         // [B,H,S,HD] 8MB (pre-scaled, log2 domain)
  bf16* kh  = (bf16*)(ws + 16ull * 1024 * 1024);        // [B,H,S,HD] 8MB
  bf16* vT  = (bf16*)(ws + 24ull * 1024 * 1024);        // [B,H,HD,S] 8MB
  bf16* ctx = (bf16*)(ws + 32ull * 1024 * 1024);        // [B,S,D]    8MB  (aliases qb: qb dead before attn)
  bf16* qb  = ctx;                                      // bf16 Q tokens (pre-scaled), 8MB
  bf16* kb  = (bf16*)(ws + 40ull * 1024 * 1024);        // bf16 K tokens 8MB
  bf16* vb  = (bf16*)(ws + 48ull * 1024 * 1024);        // bf16 V tokens 8MB -> 56MB total
  float* out = (float*)d_out;

  bool big = ws_size >= 56ull * 1024 * 1024;  // ws_size fixed per harness -> deterministic

  if (big) {
    front_kernel<<<dim3(1024, 7), 256, 0, stream>>>(Wq, Wk, Wv, Wo, WT, Q, K, V, qb, kb, vb, vl);
    proj_gemm_b<<<dim3(256, 3), 256, 0, stream>>>(qb, kb, vb, WT, qh, kh, vT, vl);
  } else {
    wcast_kernel<<<dim3(32, 32, 4), 256, 0, stream>>>(Wq, Wk, Wv, Wo, WT);
    proj_gemm<<<dim3(256, 3), 256, 0, stream>>>(Q, K, V, WT, qh, kh, vT);
  }
  attn_kernel<<<dim3(1024), 256, 0, stream>>>(qh, kh, vT, vl, ctx);
  out_gemm<<<dim3(512), 256, 0, stream>>>(ctx, WT + 3ull * D_ * D_, out);
}

// Round 13
// 215.801 us; speedup vs baseline: 1.1854x; 1.1854x over previous
//
#include <hip/hip_runtime.h>
#include <stdint.h>

#define B_ 2
#define S_ 2048
#define D_ 1024
#define H_ 16
#define HD_ 64
#define MG_ (B_*S_)
#define MASKV -1000000.0f
#define LP_ 72   // Ps row stride (bf16): conflict-free b128
#define LO_ 68   // merge buffer row stride (f32)
#define M2_ 17.3f  // fixed softmax max, log2 domain
#define QSCALE_ (0.125f * 1.44269504088896f)  // 1/sqrt(HD) * log2(e)

typedef __bf16 bf16;
typedef bf16 bf16x8 __attribute__((ext_vector_type(8)));
typedef bf16 bf16x4 __attribute__((ext_vector_type(4)));
typedef float f32x4 __attribute__((ext_vector_type(4)));

#define MFMA(a, b, c) __builtin_amdgcn_mfma_f32_16x16x32_bf16(a, b, c, 0, 0, 0)

// async global->LDS, 16 B per lane; lds dest = wave-uniform base + lane*16
__device__ __forceinline__ void gl_lds16(const bf16* g, bf16* l) {
  __builtin_amdgcn_global_load_lds((const __attribute__((address_space(1))) void*)g,
                                   (__attribute__((address_space(3))) void*)l, 16, 0, 0);
}

// K rows needed per batch: keys >= ceil64(valid) are unobservable (P==0 exactly).
// valid==0 -> reference does uniform softmax over ALL positions -> need everything.
__device__ __forceinline__ int kneed_of(int valid) {
  return (valid == 0) ? S_ : ((valid + 63) & ~63);
}

// ---------------- fused front end ----------------
// planes 0..3: WT[n][k] = (bf16)W[k][n]  (32x32 transpose tiles)
// planes 4..6: Q/K/V f32->bf16 cast (Q pre-scaled); K/V strips beyond
//              ceil128(kneed) skipped (proj reads full 128-row strips).
__global__ __launch_bounds__(256) void front_kernel(const float* __restrict__ W0, const float* __restrict__ W1,
                                                    const float* __restrict__ W2, const float* __restrict__ W3,
                                                    bf16* __restrict__ T, const float* __restrict__ Qin,
                                                    const float* __restrict__ Kin, const float* __restrict__ Vin,
                                                    bf16* __restrict__ qb, bf16* __restrict__ kb,
                                                    bf16* __restrict__ vb, const int* __restrict__ vlen) {
  __shared__ float tile[32][33];
  int z = blockIdx.y;
  if (z < 4) {
    const float* W = z == 0 ? W0 : z == 1 ? W1 : z == 2 ? W2 : W3;
    bf16* Tz = T + (size_t)z * D_ * D_;
    int tx = threadIdx.x & 31, ty = threadIdx.x >> 5;
    int bn = (blockIdx.x & 31) * 32, bk = (blockIdx.x >> 5) * 32;
#pragma unroll
    for (int i = 0; i < 32; i += 8)
      tile[ty + i][tx] = W[(size_t)(bk + ty + i) * D_ + bn + tx];
    __syncthreads();
#pragma unroll
    for (int i = 0; i < 32; i += 8)
      Tz[(size_t)(bn + ty + i) * D_ + bk + tx] = (bf16)tile[tx][ty + i];
  } else {
    int t = z - 4;
    const float* src = t == 0 ? Qin : t == 1 ? Kin : Vin;
    bf16* dst = t == 0 ? qb : t == 1 ? kb : vb;
    float sc = t == 0 ? QSCALE_ : 1.0f;
    if (t) {  // K/V: skip strips no proj block will read
      int m0 = blockIdx.x * 4;  // 4 tokens per block
      int b = m0 >> 11, s0 = m0 & (S_ - 1);
      int kneed128 = (kneed_of(vlen[b]) + 127) & ~127;
      if (s0 >= kneed128) return;
    }
    size_t base4 = (size_t)blockIdx.x * 1024 + threadIdx.x;  // float4 index
#pragma unroll
    for (int j = 0; j < 4; ++j) {
      size_t i4 = base4 + (size_t)j * 256;
      float4 v = *(const float4*)&src[i4 * 4];
      bf16x4 bv; bv[0] = (bf16)(v.x * sc); bv[1] = (bf16)(v.y * sc);
      bv[2] = (bf16)(v.z * sc); bv[3] = (bf16)(v.w * sc);
      *(bf16x4*)&dst[i4 * 4] = bv;
    }
  }
}

// ---------------- fused projections, pure-bf16, both operands async, vlen-gated ----------------
// mode 0: qh = qb @ Wq (qb pre-scaled) ; mode 1: kh = kb @ Wk ; mode 2: vT = (vb @ Wv)^T
// modes 1/2: token strips with s0 >= kneed produce only unobservable K/V rows -> skip.
__global__ __launch_bounds__(256) void proj_gemm_b(const bf16* __restrict__ qb, const bf16* __restrict__ kb,
                                                   const bf16* __restrict__ vb, const bf16* __restrict__ WT,
                                                   bf16* __restrict__ qh, bf16* __restrict__ kh,
                                                   bf16* __restrict__ vT, const int* __restrict__ vlen) {
  __shared__ alignas(16) bf16 Sa[128 * 32];  // token rows
  __shared__ alignas(16) bf16 Sw[128 * 32];  // WT rows
  int mode = blockIdx.y;
  int bx = blockIdx.x;
  int i1 = (bx & 7) + ((bx >> 6) << 3);  // heavy strip (tokens), 0..31
  int i2 = (bx >> 3) & 7;                // light strip (WT), 0..7
  if (mode >= 1) {
    int m0tok = i1 * 128;
    int b = m0tok >> 11, s0 = m0tok & (S_ - 1);
    if (s0 >= kneed_of(vlen[b])) return;
  }
  int tid = threadIdx.x, lane = tid & 63, w = tid >> 6;
  int wm = w >> 1, wn = w & 1, ml = lane & 15, quad = lane >> 4;
  int l4 = lane >> 2, k8 = (lane & 3) * 8;
  f32x4 acc[4][4] = {};

  const bf16* Tok = mode == 0 ? qb : mode == 1 ? kb : vb;
  const bf16* Hp = WT + (size_t)mode * D_ * D_;
  int frow0 = i1 * 128, hrow0 = i2 * 128;
  bf16* Xs = (mode < 2) ? Sa : Sw;  // MFMA A-side
  bf16* Ys = (mode < 2) ? Sw : Sa;  // MFMA B-side

  for (int kk = 0; kk < D_; kk += 32) {
    __syncthreads();
#pragma unroll
    for (int j = 0; j < 2; ++j) {
      int chunk = w * 2 + j;
      gl_lds16(&Tok[(size_t)(frow0 + chunk * 16 + l4) * D_ + kk + k8], &Sa[chunk * 16 * 32]);
      gl_lds16(&Hp[(size_t)(hrow0 + chunk * 16 + l4) * D_ + kk + k8], &Sw[chunk * 16 * 32]);
    }
    __syncthreads();
    bf16x8 af[4], bfr[4];
#pragma unroll
    for (int mt = 0; mt < 4; ++mt) af[mt] = *(bf16x8*)&Xs[(wm * 64 + mt * 16 + ml) * 32 + quad * 8];
#pragma unroll
    for (int nt = 0; nt < 4; ++nt) bfr[nt] = *(bf16x8*)&Ys[(wn * 64 + nt * 16 + ml) * 32 + quad * 8];
#pragma unroll
    for (int mt = 0; mt < 4; ++mt)
#pragma unroll
      for (int nt = 0; nt < 4; ++nt)
        acc[mt][nt] = MFMA(af[mt], bfr[nt], acc[mt][nt]);
  }

  if (mode < 2) {
    bf16* dst = mode ? kh : qh;
    int m0 = i1 * 128, n0 = i2 * 128;
#pragma unroll
    for (int mt = 0; mt < 4; ++mt)
#pragma unroll
      for (int nt = 0; nt < 4; ++nt)
#pragma unroll
        for (int r = 0; r < 4; ++r) {
          int m = m0 + wm * 64 + mt * 16 + quad * 4 + r;
          int n = n0 + wn * 64 + nt * 16 + ml;
          int b = m >> 11, s = m & (S_ - 1), h = n >> 6, hd = n & 63;
          dst[(((size_t)(b * H_ + h)) * S_ + s) * HD_ + hd] = (bf16)acc[mt][nt][r];
        }
  } else {
    int m0 = i2 * 128, n0 = i1 * 128;
#pragma unroll
    for (int mt = 0; mt < 4; ++mt)
#pragma unroll
      for (int nt = 0; nt < 4; ++nt)
#pragma unroll
        for (int r = 0; r < 4; ++r) {
          int dcol = m0 + wm * 64 + mt * 16 + quad * 4 + r;  // d
          int n = n0 + wn * 64 + nt * 16 + ml;               // token
          int b = n >> 11, s = n & (S_ - 1), h = dcol >> 6, hd = dcol & 63;
          vT[(((size_t)(b * H_ + h)) * HD_ + hd) * S_ + s] = (bf16)acc[mt][nt][r];
        }
  }
}

// ---------------- fallback wcast (small-ws path only) ----------------
__global__ __launch_bounds__(256) void wcast_kernel(const float* __restrict__ W0, const float* __restrict__ W1,
                                                    const float* __restrict__ W2, const float* __restrict__ W3,
                                                    bf16* __restrict__ T) {
  const float* W = blockIdx.z == 0 ? W0 : blockIdx.z == 1 ? W1 : blockIdx.z == 2 ? W2 : W3;
  bf16* Tz = T + (size_t)blockIdx.z * D_ * D_;
  __shared__ float tile[32][33];
  int tx = threadIdx.x & 31, ty = threadIdx.x >> 5;
  int bn = blockIdx.x * 32, bk = blockIdx.y * 32;
#pragma unroll
  for (int i = 0; i < 32; i += 8)
    tile[ty + i][tx] = W[(size_t)(bk + ty + i) * D_ + bn + tx];
  __syncthreads();
#pragma unroll
  for (int i = 0; i < 32; i += 8)
    Tz[(size_t)(bn + ty + i) * D_ + bk + tx] = (bf16)tile[tx][ty + i];
}

// ---------------- fallback projections (round-5 exact, f32 inputs) ----------------
__global__ __launch_bounds__(256) void proj_gemm(const float* __restrict__ Qin, const float* __restrict__ Kin,
                                                 const float* __restrict__ Vin, const bf16* __restrict__ WT,
                                                 bf16* __restrict__ qh, bf16* __restrict__ kh,
                                                 bf16* __restrict__ vT) {
  __shared__ alignas(16) bf16 Asf[128 * 32];
  __shared__ alignas(16) bf16 Ash[128 * 32];
  int mode = blockIdx.y;
  int bx = blockIdx.x;
  int i1 = (bx & 7) + ((bx >> 6) << 3);
  int i2 = (bx >> 3) & 7;
  int tid = threadIdx.x, lane = tid & 63, w = tid >> 6;
  int wm = w >> 1, wn = w & 1, ml = lane & 15, quad = lane >> 4;
  int rr = tid >> 3, c4 = (tid & 7) * 4;
  int l4 = lane >> 2, k8 = (lane & 3) * 8;
  f32x4 acc[4][4] = {};

  const float* Fp = mode == 0 ? Qin : mode == 1 ? Kin : Vin;
  const bf16* Hp = WT + (size_t)mode * D_ * D_;
  int frow0 = i1 * 128, hrow0 = i2 * 128;
  bf16* Xs = (mode < 2) ? Asf : Ash;
  bf16* Ys = (mode < 2) ? Ash : Asf;

  for (int kk = 0; kk < D_; kk += 32) {
    __syncthreads();
#pragma unroll
    for (int j = 0; j < 2; ++j) {
      int chunk = w * 2 + j;
      gl_lds16(&Hp[(size_t)(hrow0 + chunk * 16 + l4) * D_ + kk + k8], &Ash[chunk * 16 * 32]);
    }
#pragma unroll
    for (int p = 0; p < 4; ++p) {
      float4 v = *(const float4*)&Fp[(size_t)(frow0 + rr + p * 32) * D_ + kk + c4];
      bf16x4 bv; bv[0] = (bf16)v.x; bv[1] = (bf16)v.y; bv[2] = (bf16)v.z; bv[3] = (bf16)v.w;
      *(bf16x4*)&Asf[(rr + p * 32) * 32 + c4] = bv;
    }
    __syncthreads();
    bf16x8 af[4], bfr[4];
#pragma unroll
    for (int mt = 0; mt < 4; ++mt) af[mt] = *(bf16x8*)&Xs[(wm * 64 + mt * 16 + ml) * 32 + quad * 8];
#pragma unroll
    for (int nt = 0; nt < 4; ++nt) bfr[nt] = *(bf16x8*)&Ys[(wn * 64 + nt * 16 + ml) * 32 + quad * 8];
#pragma unroll
    for (int mt = 0; mt < 4; ++mt)
#pragma unroll
      for (int nt = 0; nt < 4; ++nt)
        acc[mt][nt] = MFMA(af[mt], bfr[nt], acc[mt][nt]);
  }

  if (mode < 2) {
    bf16* dst = mode ? kh : qh;
    float oscale = mode ? 1.0f : QSCALE_;
    int m0 = i1 * 128, n0 = i2 * 128;
#pragma unroll
    for (int mt = 0; mt < 4; ++mt)
#pragma unroll
      for (int nt = 0; nt < 4; ++nt)
#pragma unroll
        for (int r = 0; r < 4; ++r) {
          int m = m0 + wm * 64 + mt * 16 + quad * 4 + r;
          int n = n0 + wn * 64 + nt * 16 + ml;
          int b = m >> 11, s = m & (S_ - 1), h = n >> 6, hd = n & 63;
          dst[(((size_t)(b * H_ + h)) * S_ + s) * HD_ + hd] = (bf16)(acc[mt][nt][r] * oscale);
        }
  } else {
    int m0 = i2 * 128, n0 = i1 * 128;
#pragma unroll
    for (int mt = 0; mt < 4; ++mt)
#pragma unroll
      for (int nt = 0; nt < 4; ++nt)
#pragma unroll
        for (int r = 0; r < 4; ++r) {
          int dcol = m0 + wm * 64 + mt * 16 + quad * 4 + r;
          int n = n0 + wn * 64 + nt * 16 + ml;
          int b = n >> 11, s = n & (S_ - 1), h = dcol >> 6, hd = dcol & 63;
          vT[(((size_t)(b * H_ + h)) * HD_ + hd) * S_ + s] = (bf16)acc[mt][nt][r];
        }
  }
}

// ---------------- barrier-free flash attention, fixed-max softmax (round-5 exact) ----------------
// Decode note: bh = (bx&7) + ((bx>>8)<<3). With round-robin block->CU at stride
// gridDim/CUs = 4, each CU gets blocks {i, i+256, i+512, i+768} whose b-bit (bx
// bit 9) differs -> every CU holds 2 long + 2 short blocks. Verified: moving b
// to bx bit 3 (r6/r12) makes all 4 same-batch -> 104 µs vs 64 µs. DO NOT TOUCH.
__global__ __launch_bounds__(256) void attn_kernel(const bf16* __restrict__ qh, const bf16* __restrict__ kh,
                                                   const bf16* __restrict__ vT, const int* __restrict__ vlen,
                                                   bf16* __restrict__ ctx) {
  __shared__ alignas(16) char ldsraw[35328];
  bf16* Ps = (bf16*)ldsraw;                    // [4 waves][32 rows][LP_]
  float* Om = (float*)ldsraw;                  // [4 waves][32 rows][LO_] (union, post-loop)
  float* Lv = (float*)(ldsraw + 34816);        // [4 waves][32 rows]

  int tid = threadIdx.x, lane = tid & 63, w = tid >> 6;
  int ml = lane & 15, quad = lane >> 4;
  int wq = w >> 1, wk = w & 1;
  int bx = blockIdx.x;
  int bh = (bx & 7) + ((bx >> 8) << 3);  // same-bh -> same XCD (K/V L2-resident)
  int qt = (bx >> 3) & 31;
  int b = bh >> 4, h = bh & 15;
  const bf16* qbase = qh + ((size_t)bh * S_ + qt * 64 + wq * 32) * HD_;
  const bf16* kbase = kh + (size_t)bh * S_ * HD_;
  const bf16* vbase = vT + (size_t)bh * HD_ * S_;
  int valid = vlen[b];
  int nkt = (valid == 0) ? (S_ / 64) : ((valid + 63) >> 6);

  bf16x8 aq[2][2];
#pragma unroll
  for (int mt = 0; mt < 2; ++mt)
#pragma unroll
    for (int half = 0; half < 2; ++half)
      aq[mt][half] = *(const bf16x8*)&qbase[(mt * 16 + ml) * HD_ + half * 32 + quad * 8];

  bf16 onev = (bf16)1.0f;
  bf16x8 ones = {onev, onev, onev, onev, onev, onev, onev, onev};

  f32x4 o[2][4] = {};
  f32x4 lacc[2] = {};

  bf16* Pw = Ps + (size_t)w * 32 * LP_;

  for (int kt = wk; kt < nkt; kt += 2) {
    const bf16* kp = kbase + (size_t)kt * 64 * HD_;
    bool tail = (kt * 64 + 64 > valid);
    bf16x8 bk[4][2];
#pragma unroll
    for (int nt = 0; nt < 4; ++nt)
#pragma unroll
      for (int half = 0; half < 2; ++half)
        bk[nt][half] = *(const bf16x8*)&kp[(nt * 16 + ml) * HD_ + half * 32 + quad * 8];

#pragma unroll
    for (int mt = 0; mt < 2; ++mt) {
      f32x4 sc[4];
#pragma unroll
      for (int nt = 0; nt < 4; ++nt) {
        f32x4 c = {};
        c = MFMA(aq[mt][0], bk[nt][0], c);
        c = MFMA(aq[mt][1], bk[nt][1], c);
        sc[nt] = c;
      }
#pragma unroll
      for (int r = 0; r < 4; ++r) {
#pragma unroll
        for (int nt = 0; nt < 4; ++nt) {
          float s = sc[nt][r];
          if (tail) {
            int col = kt * 64 + nt * 16 + ml;
            if (col >= valid) s = MASKV;
          }
          if (valid == 0) s = 0.f;  // uniform softmax (all-masked case)
          float p = exp2f(s - M2_);
          Pw[(mt * 16 + quad * 4 + r) * LP_ + nt * 16 + ml] = (bf16)p;
        }
      }
    }
    // PV + l-sum: wave-private P (compiler inserts lgkmcnt wait; no barrier)
#pragma unroll
    for (int ks = 0; ks < 2; ++ks) {
      bf16x8 bv[4];
#pragma unroll
      for (int ht = 0; ht < 4; ++ht)
        bv[ht] = *(const bf16x8*)&vbase[(size_t)(ht * 16 + ml) * S_ + kt * 64 + ks * 32 + quad * 8];
#pragma unroll
      for (int mt = 0; mt < 2; ++mt) {
        bf16x8 ap = *(bf16x8*)&Pw[(mt * 16 + ml) * LP_ + ks * 32 + quad * 8];
        lacc[mt] = MFMA(ap, ones, lacc[mt]);
#pragma unroll
        for (int ht = 0; ht < 4; ++ht) o[mt][ht] = MFMA(ap, bv[ht], o[mt][ht]);
      }
    }
  }

  // ---- sum-merge across wk ----
  __syncthreads();  // all waves done with Ps (union with Om)
#pragma unroll
  for (int mt = 0; mt < 2; ++mt) {
#pragma unroll
    for (int r = 0; r < 4; ++r) {
      int rl = mt * 16 + quad * 4 + r;
#pragma unroll
      for (int ht = 0; ht < 4; ++ht)
        Om[(w * 32 + rl) * LO_ + ht * 16 + ml] = o[mt][ht][r];
      if (ml == 0) Lv[w * 32 + rl] = lacc[mt][r];
    }
  }
  __syncthreads();
#pragma unroll 4
  for (int rr = 0; rr < 16; ++rr) {
    int rg = w * 16 + rr;
    int wqs = rg >> 5, rl = rg & 31;
    int s0 = (wqs * 2) * 32 + rl, s1 = (wqs * 2 + 1) * 32 + rl;
    float ls = Lv[s0] + Lv[s1];
    float ov = Om[s0 * LO_ + lane] + Om[s1 * LO_ + lane];
    ctx[((size_t)b * S_ + qt * 64 + rg) * D_ + h * 64 + lane] = (bf16)(ov / ls);
  }
}

// ---------------- output projection: 128x64 tiles, async staging, XCD-swizzled ----------------
__global__ __launch_bounds__(256) void out_gemm(const bf16* __restrict__ ctx, const bf16* __restrict__ WoT,
                                                float* __restrict__ out) {
  __shared__ alignas(16) bf16 As[128 * 32];
  __shared__ alignas(16) bf16 Bs[64 * 32];
  int bx = blockIdx.x;  // flat 512
  int mt8 = (bx & 7) + ((bx >> 7) << 3);  // m-tile 0..31 (same-m -> same XCD)
  int ntile = (bx >> 3) & 15;             // n-tile 0..15
  int tid = threadIdx.x, lane = tid & 63, w = tid >> 6;
  int wm = w >> 1, wn = w & 1, ml = lane & 15, quad = lane >> 4;
  int l4 = lane >> 2, k8 = (lane & 3) * 8;
  int m0 = mt8 * 128, n0 = ntile * 64;
  f32x4 acc[4][2] = {};
  for (int kk = 0; kk < D_; kk += 32) {
    __syncthreads();
#pragma unroll
    for (int j = 0; j < 2; ++j) {
      int chunk = w * 2 + j;
      gl_lds16(&ctx[(size_t)(m0 + chunk * 16 + l4) * D_ + kk + k8], &As[chunk * 16 * 32]);
    }
    gl_lds16(&WoT[(size_t)(n0 + w * 16 + l4) * D_ + kk + k8], &Bs[w * 16 * 32]);
    __syncthreads();
    bf16x8 af[4], bfr[2];
#pragma unroll
    for (int mt = 0; mt < 4; ++mt) af[mt] = *(bf16x8*)&As[(wm * 64 + mt * 16 + ml) * 32 + quad * 8];
#pragma unroll
    for (int nt = 0; nt < 2; ++nt) bfr[nt] = *(bf16x8*)&Bs[(wn * 32 + nt * 16 + ml) * 32 + quad * 8];
#pragma unroll
    for (int mt = 0; mt < 4; ++mt)
#pragma unroll
      for (int nt = 0; nt < 2; ++nt)
        acc[mt][nt] = MFMA(af[mt], bfr[nt], acc[mt][nt]);
  }
#pragma unroll
  for (int mt = 0; mt < 4; ++mt)
#pragma unroll
    for (int nt = 0; nt < 2; ++nt)
#pragma unroll
      for (int r = 0; r < 4; ++r) {
        int m = m0 + wm * 64 + mt * 16 + quad * 4 + r;
        int n = n0 + wn * 32 + nt * 16 + ml;
        out[(size_t)m * D_ + n] = acc[mt][nt][r];
      }
}

extern "C" void kernel_launch(void* const* d_in, const int* in_sizes, int n_in,
                              void* d_out, int out_size, void* d_ws, size_t ws_size,
                              hipStream_t stream) {
  const float* Q = (const float*)d_in[0];
  const float* K = (const float*)d_in[1];
  const float* V = (const float*)d_in[2];
  const int* vl = (const int*)d_in[3];
  const float* Wq = (const float*)d_in[4];
  const float* Wk = (const float*)d_in[5];
  const float* Wv = (const float*)d_in[6];
  const float* Wo = (const float*)d_in[7];
  char* ws = (char*)d_ws;
  bf16* WT  = (bf16*)ws;                                // 4 x 2MB (WqT, WkT, WvT, WoT)
  bf16* qh  = (bf16*)(ws + 8ull * 1024 * 1024);         // [B,H,S,HD] 8MB (pre-scaled, log2 domain)
  bf16* kh  = (bf16*)(ws + 16ull * 1024 * 1024);        // [B,H,S,HD] 8MB
  bf16* vT  = (bf16*)(ws + 24ull * 1024 * 1024);        // [B,H,HD,S] 8MB
  bf16* ctx = (bf16*)(ws + 32ull * 1024 * 1024);        // [B,S,D]    8MB  (aliases qb: qb dead before attn)
  bf16* qb  = ctx;                                      // bf16 Q tokens (pre-scaled), 8MB
  bf16* kb  = (bf16*)(ws + 40ull * 1024 * 1024);        // bf16 K tokens 8MB
  bf16* vb  = (bf16*)(ws + 48ull * 1024 * 1024);        // bf16 V tokens 8MB -> 56MB total
  float* out = (float*)d_out;

  bool big = ws_size >= 56ull * 1024 * 1024;  // ws_size fixed per harness -> deterministic

  if (big) {
    front_kernel<<<dim3(1024, 7), 256, 0, stream>>>(Wq, Wk, Wv, Wo, WT, Q, K, V, qb, kb, vb, vl);
    proj_gemm_b<<<dim3(256, 3), 256, 0, stream>>>(qb, kb, vb, WT, qh, kh, vT, vl);
  } else {
    wcast_kernel<<<dim3(32, 32, 4), 256, 0, stream>>>(Wq, Wk, Wv, Wo, WT);
    proj_gemm<<<dim3(256, 3), 256, 0, stream>>>(Q, K, V, WT, qh, kh, vT);
  }
  attn_kernel<<<dim3(1024), 256, 0, stream>>>(qh, kh, vT, vl, ctx);
  out_gemm<<<dim3(512), 256, 0, stream>>>(ctx, WT + 3ull * D_ * D_, out);
}